// Round 2
// baseline (3475.005 us; speedup 1.0000x reference)
//
#include <hip/hip_runtime.h>

#define N_NODES 165888
#define N_EDGES 3317760
#define HID 64
#define N_LAYERS 4
#define LN_EPS 1e-5f

__device__ __forceinline__ float wave_sum64(float v) {
    #pragma unroll
    for (int off = 32; off >= 1; off >>= 1)
        v += __shfl_xor(v, off, 64);
    return v;
}

// ---------------- CSR build ----------------

__global__ void k_hist(const int* __restrict__ dst, int* __restrict__ cnt) {
    int stride = gridDim.x * blockDim.x;
    for (int e = blockIdx.x * blockDim.x + threadIdx.x; e < N_EDGES; e += stride)
        atomicAdd(&cnt[dst[e]], 1);
}

__global__ void k_scan_block(const int* __restrict__ cnt, int* __restrict__ roff,
                             int* __restrict__ blksum) {
    __shared__ int s[256];
    int t = threadIdx.x;
    int i = blockIdx.x * 256 + t;
    int own = cnt[i];
    s[t] = own;
    __syncthreads();
    for (int off = 1; off < 256; off <<= 1) {
        int v = (t >= off) ? s[t - off] : 0;
        __syncthreads();
        s[t] += v;
        __syncthreads();
    }
    roff[i] = s[t] - own;            // exclusive within block
    if (t == 255) blksum[blockIdx.x] = s[255];
}

// one block, 1024 threads: parallel scan of the 648 block sums
__global__ void k_scan_tops(const int* __restrict__ blksum, int* __restrict__ blkoff,
                            int* __restrict__ roff) {
    __shared__ int s[1024];
    int t = threadIdx.x;
    int v = (t < N_NODES / 256) ? blksum[t] : 0;
    s[t] = v;
    __syncthreads();
    for (int off = 1; off < 1024; off <<= 1) {
        int u = (t >= off) ? s[t - off] : 0;
        __syncthreads();
        s[t] += u;
        __syncthreads();
    }
    if (t < N_NODES / 256) blkoff[t] = s[t] - v;   // exclusive
    if (t == N_NODES / 256 - 1) roff[N_NODES] = s[t];
}

__global__ void k_scan_add(int* __restrict__ roff, const int* __restrict__ blkoff) {
    int stride = gridDim.x * blockDim.x;
    for (int i = blockIdx.x * blockDim.x + threadIdx.x; i < N_NODES; i += stride)
        roff[i] += blkoff[i >> 8];
}

__global__ void k_fill(const int* __restrict__ src, const int* __restrict__ dst,
                       const int* __restrict__ roff, int* __restrict__ cur,
                       int* __restrict__ csr) {
    int stride = gridDim.x * blockDim.x;
    for (int e = blockIdx.x * blockDim.x + threadIdx.x; e < N_EDGES; e += stride) {
        int d = dst[e];
        int p = atomicAdd(&cur[d], 1);
        csr[roff[d] + p] = src[e];
    }
}

// ---------------- input projection + residual (barrier-free main loop) ----------------

__global__ __launch_bounds__(256) void k_proj(
        const float* __restrict__ x,
        const float* __restrict__ Win, const float* __restrict__ bin,
        const float* __restrict__ Wres, const float* __restrict__ bres,
        float* __restrict__ h0, float* __restrict__ res) {
    __shared__ float wt[64 * 64];      // wt[k*64+j] = Wres[j][k]
    for (int idx = threadIdx.x; idx < 4096; idx += 256) {
        int j = idx >> 6, k = idx & 63;
        wt[k * 64 + j] = Wres[idx];
    }
    __syncthreads();
    int lane = threadIdx.x & 63;
    int w = threadIdx.x >> 6;
    float bi = bin[lane], br = bres[lane];
    const int G = N_NODES / 4;
    for (int g = blockIdx.x; g < G; g += gridDim.x) {
        int n = g * 4 + w;
        float hv = bi;
        #pragma unroll
        for (int k = 0; k < 9; ++k)
            hv += x[n * 9 + k] * Win[lane * 9 + k];
        h0[(size_t)n * 64 + lane] = hv;
        float r = br;
        #pragma unroll
        for (int k = 0; k < 64; ++k)
            r += wt[k * 64 + lane] * __shfl(hv, k);
        res[(size_t)n * 64 + lane] = r;
    }
}

// ---------------- fused GraphConv layer, barrier-free ----------------
// wave handles 4 nodes: float4 gather (4 edges in flight / 16-lane groups),
// csr indices prefetched to per-wave LDS, matvec via LDS weights + readlane
// broadcasts, LN via shuffle reduce.

__global__ __launch_bounds__(256) void k_layer(
        const float* __restrict__ hprev, float* __restrict__ hnext,
        const float* __restrict__ res,
        const int* __restrict__ roff, const int* __restrict__ csr,
        const float* __restrict__ Wroot, const float* __restrict__ Wrel,
        const float* __restrict__ bconv,
        const float* __restrict__ lng, const float* __restrict__ lnb) {
    __shared__ float wtr[64 * 64];     // wtr[k*64+j] = Wroot[j][k]
    __shared__ float wtl[64 * 64];     // wtl[k*64+j] = Wrel[j][k]
    __shared__ int   idxb[4][192];     // per-wave csr index prefetch
    for (int t = threadIdx.x; t < 4096; t += 256) {
        int j = t >> 6, k = t & 63;
        wtr[k * 64 + j] = Wroot[t];
        wtl[k * 64 + j] = Wrel[t];
    }
    __syncthreads();                   // only barrier in the kernel

    int lane = threadIdx.x & 63;
    int w = threadIdx.x >> 6;
    int li = lane & 15, gi = lane >> 4;
    int* idxw = idxb[w];
    float bc = bconv[lane], g_ = lng[lane], b_ = lnb[lane];

    const int G = N_NODES / 16;
    for (int g = blockIdx.x; g < G; g += gridDim.x) {
        int nb = g * 16 + w * 4;
        // row offsets for nodes nb..nb+4 via one load + shuffles
        int r0 = roff[nb + (lane < 5 ? lane : 4)];
        int ew0 = __shfl(r0, 0);
        int ew4 = __shfl(r0, 4);
        int ecnt = ew4 - ew0;
        // own rows + residual: issue early
        float ho[4], rv[4];
        #pragma unroll
        for (int m = 0; m < 4; ++m) {
            ho[m] = hprev[(size_t)(nb + m) * 64 + lane];
            rv[m] = res[(size_t)(nb + m) * 64 + lane];
        }
        // prefetch this wave's csr slice into LDS (same-wave, no barrier)
        for (int t = lane; t < ecnt && t < 192; t += 64)
            idxw[t] = csr[ew0 + t];

        // gather: group gi handles edges = gi (mod 4), lane li covers 4 channels
        float ax[4], ay[4], az[4], aw[4];
        #pragma unroll
        for (int m = 0; m < 4; ++m) {
            int eb = __shfl(r0, m) - ew0;
            int ee = __shfl(r0, m + 1) - ew0;
            float4 av; av.x = av.y = av.z = av.w = 0.f;
            int p = eb + gi;
            for (; p + 4 < ee; p += 8) {
                int s0 = idxw[p];
                int s1 = idxw[p + 4];
                const float4 v0 = *(const float4*)(hprev + ((size_t)s0 << 6) + (li << 2));
                const float4 v1 = *(const float4*)(hprev + ((size_t)s1 << 6) + (li << 2));
                av.x += v0.x + v1.x; av.y += v0.y + v1.y;
                av.z += v0.z + v1.z; av.w += v0.w + v1.w;
            }
            if (p < ee) {
                int s = idxw[p];
                const float4 v = *(const float4*)(hprev + ((size_t)s << 6) + (li << 2));
                av.x += v.x; av.y += v.y; av.z += v.z; av.w += v.w;
            }
            // combine the 4 groups' partials (all lanes end with full sums)
            #pragma unroll
            for (int off = 16; off <= 32; off <<= 1) {
                av.x += __shfl_xor(av.x, off, 64);
                av.y += __shfl_xor(av.y, off, 64);
                av.z += __shfl_xor(av.z, off, 64);
                av.w += __shfl_xor(av.w, off, 64);
            }
            ax[m] = av.x; ay[m] = av.y; az[m] = av.z; aw[m] = av.w;
        }

        // matvec: acc[j] = bc + sum_k Wroot[j][k] h[k] + Wrel[j][k] agg[k]
        float acc[4] = {bc, bc, bc, bc};
        #pragma unroll
        for (int k4 = 0; k4 < 16; ++k4) {
            float w0[4], w1[4];
            #pragma unroll
            for (int q = 0; q < 4; ++q) {
                w0[q] = wtr[(k4 * 4 + q) * 64 + lane];
                w1[q] = wtl[(k4 * 4 + q) * 64 + lane];
            }
            #pragma unroll
            for (int m = 0; m < 4; ++m) {
                acc[m] += w0[0] * __shfl(ho[m], k4 * 4 + 0) + w1[0] * __shfl(ax[m], k4)
                        + w0[1] * __shfl(ho[m], k4 * 4 + 1) + w1[1] * __shfl(ay[m], k4)
                        + w0[2] * __shfl(ho[m], k4 * 4 + 2) + w1[2] * __shfl(az[m], k4)
                        + w0[3] * __shfl(ho[m], k4 * 4 + 3) + w1[3] * __shfl(aw[m], k4);
            }
        }

        // LN + leaky relu + residual
        #pragma unroll
        for (int m = 0; m < 4; ++m) {
            float v = acc[m];
            float mu = wave_sum64(v) * (1.f / 64.f);
            float d = v - mu;
            float var = wave_sum64(d * d) * (1.f / 64.f);
            float y = d * rsqrtf(var + LN_EPS) * g_ + b_;
            y = (y > 0.f) ? y : 0.01f * y;
            y += rv[m];
            hnext[(size_t)(nb + m) * 64 + lane] = y;
        }
    }
}

// ---------------- output projection: wave per node, coalesced ----------------

__global__ __launch_bounds__(256) void k_out(
        const float* __restrict__ h, const float* __restrict__ Wout,
        const float* __restrict__ bout, float* __restrict__ out) {
    int lane = threadIdx.x & 63;
    int w = threadIdx.x >> 6;
    const int G = N_NODES / 4;
    for (int g = blockIdx.x; g < G; g += gridDim.x) {
        int n = g * 4 + w;
        float hv = h[(size_t)n * 64 + lane];
        float o = 0.f;
        #pragma unroll
        for (int c = 0; c < 9; ++c) {
            float s = wave_sum64(hv * Wout[c * 64 + lane]);
            if (lane == c) o = s + bout[c];
        }
        if (lane < 9) out[(size_t)n * 9 + lane] = o;
    }
}

extern "C" void kernel_launch(void* const* d_in, const int* in_sizes, int n_in,
                              void* d_out, int out_size, void* d_ws, size_t ws_size,
                              hipStream_t stream) {
    const float* x     = (const float*)d_in[0];
    const int*   ei    = (const int*)d_in[1];     // [2, E] int32
    const float* Win   = (const float*)d_in[2];
    const float* bin   = (const float*)d_in[3];
    const float* Wrel  = (const float*)d_in[4];   // [4,64,64]
    const float* Wroot = (const float*)d_in[5];   // [4,64,64]
    const float* bconv = (const float*)d_in[6];   // [4,64]
    const float* Wres  = (const float*)d_in[7];
    const float* bres  = (const float*)d_in[8];
    const float* lng   = (const float*)d_in[9];
    const float* lnb   = (const float*)d_in[10];
    const float* Wout  = (const float*)d_in[11];
    const float* bout  = (const float*)d_in[12];
    float* out = (float*)d_out;

    char* p = (char*)d_ws;
    auto alloc = [&](size_t bytes) {
        char* r = p;
        p += (bytes + 255) & ~(size_t)255;
        return r;
    };
    float* h0   = (float*)alloc((size_t)N_NODES * 64 * 4);
    float* h1   = (float*)alloc((size_t)N_NODES * 64 * 4);
    float* res  = (float*)alloc((size_t)N_NODES * 64 * 4);
    int* csr    = (int*)alloc((size_t)N_EDGES * 4);
    int* cnt    = (int*)alloc((size_t)N_NODES * 4);
    int* cur    = (int*)alloc((size_t)N_NODES * 4);
    int* roff   = (int*)alloc((size_t)(N_NODES + 1) * 4);
    int* blk    = (int*)alloc(1024 * 4);
    int* blkoff = (int*)alloc(1024 * 4);

    const int* srcv = ei;
    const int* dstv = ei + N_EDGES;

    hipMemsetAsync(cnt, 0, (size_t)N_NODES * 4, stream);
    hipMemsetAsync(cur, 0, (size_t)N_NODES * 4, stream);
    k_hist<<<2048, 256, 0, stream>>>(dstv, cnt);
    k_scan_block<<<N_NODES / 256, 256, 0, stream>>>(cnt, roff, blk);
    k_scan_tops<<<1, 1024, 0, stream>>>(blk, blkoff, roff);
    k_scan_add<<<648, 256, 0, stream>>>(roff, blkoff);
    k_fill<<<2048, 256, 0, stream>>>(srcv, dstv, roff, cur, csr);

    k_proj<<<2592, 256, 0, stream>>>(x, Win, bin, Wres, bres, h0, res);

    float* ha = h0;
    float* hb = h1;
    for (int l = 0; l < N_LAYERS; ++l) {
        k_layer<<<2592, 256, 0, stream>>>(ha, hb, res, roff, csr,
                                          Wroot + (size_t)l * 64 * 64,
                                          Wrel + (size_t)l * 64 * 64,
                                          bconv + l * 64, lng, lnb);
        float* t = ha; ha = hb; hb = t;
    }
    k_out<<<2592, 256, 0, stream>>>(ha, Wout, bout, out);
}

// Round 4
// 779.550 us; speedup vs baseline: 4.4577x; 4.4577x over previous
//
#include <hip/hip_runtime.h>

#define N_NODES 165888
#define N_EDGES 3317760
#define LN_EPS 1e-5f

typedef _Float16 f16;
typedef _Float16 half8 __attribute__((ext_vector_type(8)));
typedef float f32x4 __attribute__((ext_vector_type(4)));

__device__ __forceinline__ f32x4 mfma16(half8 a, half8 b, f32x4 c) {
    return __builtin_amdgcn_mfma_f32_16x16x32_f16(a, b, c, 0, 0, 0);
}

// ---------------- CSR build ----------------

__global__ void k_hist(const int* __restrict__ dst, int* __restrict__ cnt) {
    int stride = gridDim.x * blockDim.x;
    for (int e = blockIdx.x * blockDim.x + threadIdx.x; e < N_EDGES; e += stride)
        atomicAdd(&cnt[dst[e]], 1);
}

__global__ void k_scan_block(const int* __restrict__ cnt, int* __restrict__ roff,
                             int* __restrict__ blksum) {
    __shared__ int s[256];
    int t = threadIdx.x;
    int i = blockIdx.x * 256 + t;
    int own = cnt[i];
    s[t] = own;
    __syncthreads();
    for (int off = 1; off < 256; off <<= 1) {
        int v = (t >= off) ? s[t - off] : 0;
        __syncthreads();
        s[t] += v;
        __syncthreads();
    }
    roff[i] = s[t] - own;
    if (t == 255) blksum[blockIdx.x] = s[255];
}

__global__ void k_scan_tops(const int* __restrict__ blksum, int* __restrict__ blkoff,
                            int* __restrict__ roff) {
    __shared__ int s[1024];
    int t = threadIdx.x;
    int v = (t < N_NODES / 256) ? blksum[t] : 0;
    s[t] = v;
    __syncthreads();
    for (int off = 1; off < 1024; off <<= 1) {
        int u = (t >= off) ? s[t - off] : 0;
        __syncthreads();
        s[t] += u;
        __syncthreads();
    }
    if (t < N_NODES / 256) blkoff[t] = s[t] - v;
    if (t == N_NODES / 256 - 1) roff[N_NODES] = s[t];
}

__global__ void k_scan_add(int* __restrict__ roff, const int* __restrict__ blkoff) {
    int stride = gridDim.x * blockDim.x;
    for (int i = blockIdx.x * blockDim.x + threadIdx.x; i < N_NODES; i += stride)
        roff[i] += blkoff[i >> 8];
}

__global__ void k_fill(const int* __restrict__ src, const int* __restrict__ dst,
                       const int* __restrict__ roff, int* __restrict__ cur,
                       int* __restrict__ csr) {
    int stride = gridDim.x * blockDim.x;
    for (int e = blockIdx.x * blockDim.x + threadIdx.x; e < N_EDGES; e += stride) {
        int d = dst[e];
        int p = atomicAdd(&cur[d], 1);
        csr[roff[d] + p] = src[e];
    }
}

// ---------------- weight conversion to fp16 ----------------
// W2h[l][j][k<128]: k<64 -> Wroot[l][j][k], k>=64 -> Wrel[l][j][k-64]
// Wresh[j][k<64]; Winh[j][k<32] (k<9 real, rest 0)

__global__ void k_wcvt(const float* __restrict__ Wroot, const float* __restrict__ Wrel,
                       const float* __restrict__ Wres, const float* __restrict__ Win,
                       f16* __restrict__ W2h, f16* __restrict__ Wresh, f16* __restrict__ Winh) {
    int i = blockIdx.x * 256 + threadIdx.x;
    if (i < 4 * 64 * 128) {
        int l = i >> 13, r = i & 8191, j = r >> 7, k = r & 127;
        float v = (k < 64) ? Wroot[l * 4096 + j * 64 + k] : Wrel[l * 4096 + j * 64 + k - 64];
        W2h[i] = (f16)v;
    } else if (i < 4 * 64 * 128 + 4096) {
        int t = i - 4 * 64 * 128;
        Wresh[t] = (f16)Wres[t];
    } else if (i < 4 * 64 * 128 + 4096 + 2048) {
        int t = i - (4 * 64 * 128 + 4096);
        int j = t >> 5, k = t & 31;
        Winh[t] = (k < 9) ? (f16)Win[j * 9 + k] : (f16)0.f;
    }
}

// ---------------- input projection + residual via MFMA ----------------

__global__ __launch_bounds__(256) void k_proj(
        const float* __restrict__ x, const f16* __restrict__ Winh,
        const float* __restrict__ bin, const f16* __restrict__ Wresh,
        const float* __restrict__ bres, f16* __restrict__ h0,
        float* __restrict__ res) {
    __shared__ f16 hs[4][16][64];
    int tid = threadIdx.x, w = tid >> 6, lane = tid & 63, li = lane & 15, kg = lane >> 4;
    int nb = blockIdx.x * 64 + w * 16;
    int node = nb + li;

    half8 ax;
    #pragma unroll
    for (int e = 0; e < 8; ++e) ax[e] = (f16)0.f;
    if (kg == 0) {
        #pragma unroll
        for (int e = 0; e < 8; ++e) ax[e] = (f16)x[(size_t)node * 9 + e];
    } else if (kg == 1) {
        ax[0] = (f16)x[(size_t)node * 9 + 8];
    }

    f32x4 ch[4];
    #pragma unroll
    for (int jt = 0; jt < 4; ++jt) {
        half8 b = *(const half8*)(Winh + (jt * 16 + li) * 32 + kg * 8);
        f32x4 z = {0.f, 0.f, 0.f, 0.f};
        ch[jt] = mfma16(ax, b, z);
    }
    #pragma unroll
    for (int jt = 0; jt < 4; ++jt) {
        float bb = bin[jt * 16 + li];
        #pragma unroll
        for (int r = 0; r < 4; ++r) {
            int row = kg * 4 + r;
            float v = ch[jt][r] + bb;
            f16 hv = (f16)v;
            h0[(size_t)(nb + row) * 64 + jt * 16 + li] = hv;
            int col = jt * 16 + li;
            hs[w][row][col ^ ((row & 7) * 8)] = hv;   // XOR-swizzle
        }
    }
    __syncthreads();

    f32x4 cr[4];
    #pragma unroll
    for (int jt = 0; jt < 4; ++jt) { f32x4 z = {0.f,0.f,0.f,0.f}; cr[jt] = z; }
    #pragma unroll
    for (int s = 0; s < 2; ++s) {
        int k0 = s * 32 + kg * 8;
        half8 a = *(const half8*)(&hs[w][li][k0 ^ ((li & 7) * 8)]);
        #pragma unroll
        for (int jt = 0; jt < 4; ++jt) {
            half8 b = *(const half8*)(Wresh + (jt * 16 + li) * 64 + k0);
            cr[jt] = mfma16(a, b, cr[jt]);
        }
    }
    #pragma unroll
    for (int jt = 0; jt < 4; ++jt) {
        float bb = bres[jt * 16 + li];
        #pragma unroll
        for (int r = 0; r < 4; ++r)
            res[(size_t)(nb + kg * 4 + r) * 64 + jt * 16 + li] = cr[jt][r] + bb;
    }
}

// ---------------- gather: wave per node, direct csr loads (no shfl on indices) ----------------

__global__ __launch_bounds__(256) void k_gather(
        const f16* __restrict__ h, const int* __restrict__ roff,
        const int* __restrict__ csr, f16* __restrict__ agg) {
    int lane = threadIdx.x & 63;
    int gwave = (blockIdx.x * blockDim.x + threadIdx.x) >> 6;
    int nw = (gridDim.x * blockDim.x) >> 6;
    int g = lane >> 3, s = lane & 7;
    for (int n = gwave; n < N_NODES; n += nw) {
        int e0 = roff[n], e1 = roff[n + 1];
        float a0 = 0, a1 = 0, a2 = 0, a3 = 0, a4 = 0, a5 = 0, a6 = 0, a7 = 0;
        int p = e0 + g;
        for (; p + 8 < e1; p += 16) {
            int i0 = csr[p];
            int i1 = csr[p + 8];
            half8 v0 = *(const half8*)(h + ((size_t)i0 << 6) + s * 8);
            half8 v1 = *(const half8*)(h + ((size_t)i1 << 6) + s * 8);
            a0 += (float)v0[0] + (float)v1[0];
            a1 += (float)v0[1] + (float)v1[1];
            a2 += (float)v0[2] + (float)v1[2];
            a3 += (float)v0[3] + (float)v1[3];
            a4 += (float)v0[4] + (float)v1[4];
            a5 += (float)v0[5] + (float)v1[5];
            a6 += (float)v0[6] + (float)v1[6];
            a7 += (float)v0[7] + (float)v1[7];
        }
        if (p < e1) {
            int i0 = csr[p];
            half8 v0 = *(const half8*)(h + ((size_t)i0 << 6) + s * 8);
            a0 += (float)v0[0]; a1 += (float)v0[1];
            a2 += (float)v0[2]; a3 += (float)v0[3];
            a4 += (float)v0[4]; a5 += (float)v0[5];
            a6 += (float)v0[6]; a7 += (float)v0[7];
        }
        // reduce across the 8 groups (full exec here: loop has reconverged)
        #pragma unroll
        for (int off = 8; off <= 32; off <<= 1) {
            a0 += __shfl_xor(a0, off, 64);
            a1 += __shfl_xor(a1, off, 64);
            a2 += __shfl_xor(a2, off, 64);
            a3 += __shfl_xor(a3, off, 64);
            a4 += __shfl_xor(a4, off, 64);
            a5 += __shfl_xor(a5, off, 64);
            a6 += __shfl_xor(a6, off, 64);
            a7 += __shfl_xor(a7, off, 64);
        }
        if (lane < 8) {
            half8 o;
            o[0] = (f16)a0; o[1] = (f16)a1; o[2] = (f16)a2; o[3] = (f16)a3;
            o[4] = (f16)a4; o[5] = (f16)a5; o[6] = (f16)a6; o[7] = (f16)a7;
            *(half8*)(agg + ((size_t)n << 6) + s * 8) = o;
        }
    }
}

// ---------------- fused update: MFMA matvec + LN + leaky + residual ----------------

__global__ __launch_bounds__(256) void k_update(
        const f16* __restrict__ h, const f16* __restrict__ agg,
        const float* __restrict__ res, const f16* __restrict__ W2h,
        const float* __restrict__ bconv, const float* __restrict__ lng,
        const float* __restrict__ lnb, f16* __restrict__ hn) {
    int tid = threadIdx.x, w = tid >> 6, lane = tid & 63, li = lane & 15, kg = lane >> 4;
    int nb = blockIdx.x * 64 + w * 16;
    int node = nb + li;

    f32x4 acc[4];
    #pragma unroll
    for (int jt = 0; jt < 4; ++jt) { f32x4 z = {0.f,0.f,0.f,0.f}; acc[jt] = z; }

    #pragma unroll
    for (int s = 0; s < 4; ++s) {
        half8 a = (s < 2)
            ? *(const half8*)(h   + ((size_t)node << 6) + s * 32 + kg * 8)
            : *(const half8*)(agg + ((size_t)node << 6) + (s - 2) * 32 + kg * 8);
        #pragma unroll
        for (int jt = 0; jt < 4; ++jt) {
            half8 b = *(const half8*)(W2h + (size_t)(jt * 16 + li) * 128 + s * 32 + kg * 8);
            acc[jt] = mfma16(a, b, acc[jt]);
        }
    }

    #pragma unroll
    for (int jt = 0; jt < 4; ++jt) {
        float bb = bconv[jt * 16 + li];
        #pragma unroll
        for (int r = 0; r < 4; ++r) acc[jt][r] += bb;
    }

    float mu[4], rstd[4];
    #pragma unroll
    for (int r = 0; r < 4; ++r) {
        float v = acc[0][r] + acc[1][r] + acc[2][r] + acc[3][r];
        v += __shfl_xor(v, 1, 64); v += __shfl_xor(v, 2, 64);
        v += __shfl_xor(v, 4, 64); v += __shfl_xor(v, 8, 64);
        mu[r] = v * (1.f / 64.f);
    }
    #pragma unroll
    for (int r = 0; r < 4; ++r) {
        float d0 = acc[0][r] - mu[r], d1 = acc[1][r] - mu[r];
        float d2 = acc[2][r] - mu[r], d3 = acc[3][r] - mu[r];
        float vv = d0 * d0 + d1 * d1 + d2 * d2 + d3 * d3;
        vv += __shfl_xor(vv, 1, 64); vv += __shfl_xor(vv, 2, 64);
        vv += __shfl_xor(vv, 4, 64); vv += __shfl_xor(vv, 8, 64);
        rstd[r] = rsqrtf(vv * (1.f / 64.f) + LN_EPS);
    }
    #pragma unroll
    for (int jt = 0; jt < 4; ++jt) {
        float gg = lng[jt * 16 + li], bb = lnb[jt * 16 + li];
        #pragma unroll
        for (int r = 0; r < 4; ++r) {
            float y = (acc[jt][r] - mu[r]) * rstd[r] * gg + bb;
            y = (y > 0.f) ? y : 0.01f * y;
            y += res[(size_t)(nb + kg * 4 + r) * 64 + jt * 16 + li];
            hn[(size_t)(nb + kg * 4 + r) * 64 + jt * 16 + li] = (f16)y;
        }
    }
}

// ---------------- output projection: node per lane ----------------

__global__ __launch_bounds__(256) void k_out(
        const f16* __restrict__ h, const float* __restrict__ Wout,
        const float* __restrict__ bout, float* __restrict__ out) {
    int node = blockIdx.x * 256 + threadIdx.x;
    float acc[9];
    #pragma unroll
    for (int c = 0; c < 9; ++c) acc[c] = bout[c];
    #pragma unroll
    for (int cc = 0; cc < 8; ++cc) {
        half8 v = *(const half8*)(h + ((size_t)node << 6) + cc * 8);
        float f[8];
        #pragma unroll
        for (int e = 0; e < 8; ++e) f[e] = (float)v[e];
        #pragma unroll
        for (int c = 0; c < 9; ++c) {
            #pragma unroll
            for (int e = 0; e < 8; ++e)
                acc[c] += f[e] * Wout[c * 64 + cc * 8 + e];
        }
    }
    #pragma unroll
    for (int c = 0; c < 9; ++c) out[(size_t)node * 9 + c] = acc[c];
}

extern "C" void kernel_launch(void* const* d_in, const int* in_sizes, int n_in,
                              void* d_out, int out_size, void* d_ws, size_t ws_size,
                              hipStream_t stream) {
    const float* x     = (const float*)d_in[0];
    const int*   ei    = (const int*)d_in[1];
    const float* Win   = (const float*)d_in[2];
    const float* bin   = (const float*)d_in[3];
    const float* Wrel  = (const float*)d_in[4];
    const float* Wroot = (const float*)d_in[5];
    const float* bconv = (const float*)d_in[6];
    const float* Wres  = (const float*)d_in[7];
    const float* bres  = (const float*)d_in[8];
    const float* lng   = (const float*)d_in[9];
    const float* lnb   = (const float*)d_in[10];
    const float* Wout  = (const float*)d_in[11];
    const float* bout  = (const float*)d_in[12];
    float* out = (float*)d_out;

    char* p = (char*)d_ws;
    auto alloc = [&](size_t bytes) {
        char* r = p;
        p += (bytes + 255) & ~(size_t)255;
        return r;
    };
    f16*   h0    = (f16*)alloc((size_t)N_NODES * 64 * 2);
    f16*   h1    = (f16*)alloc((size_t)N_NODES * 64 * 2);
    float* res   = (float*)alloc((size_t)N_NODES * 64 * 4);
    f16*   agg   = (f16*)alloc((size_t)N_NODES * 64 * 2);
    int*   csr   = (int*)alloc((size_t)N_EDGES * 4);
    int*   cnt   = (int*)alloc((size_t)N_NODES * 4);
    int*   cur   = (int*)alloc((size_t)N_NODES * 4);
    int*   roff  = (int*)alloc((size_t)(N_NODES + 1) * 4);
    int*   blk   = (int*)alloc(1024 * 4);
    int*   blkoff= (int*)alloc(1024 * 4);
    f16*   W2h   = (f16*)alloc(4 * 64 * 128 * 2);
    f16*   Wresh = (f16*)alloc(64 * 64 * 2);
    f16*   Winh  = (f16*)alloc(64 * 32 * 2);

    const int* srcv = ei;
    const int* dstv = ei + N_EDGES;

    hipMemsetAsync(cnt, 0, (size_t)N_NODES * 4, stream);
    hipMemsetAsync(cur, 0, (size_t)N_NODES * 4, stream);
    k_hist<<<2048, 256, 0, stream>>>(dstv, cnt);
    k_scan_block<<<N_NODES / 256, 256, 0, stream>>>(cnt, roff, blk);
    k_scan_tops<<<1, 1024, 0, stream>>>(blk, blkoff, roff);
    k_scan_add<<<648, 256, 0, stream>>>(roff, blkoff);
    k_fill<<<2048, 256, 0, stream>>>(srcv, dstv, roff, cur, csr);

    k_wcvt<<<152, 256, 0, stream>>>(Wroot, Wrel, Wres, Win, W2h, Wresh, Winh);
    k_proj<<<N_NODES / 64, 256, 0, stream>>>(x, Winh, bin, Wresh, bres, h0, res);

    f16* ha = h0;
    f16* hb = h1;
    for (int l = 0; l < 4; ++l) {
        k_gather<<<4096, 256, 0, stream>>>(ha, roff, csr, agg);
        k_update<<<N_NODES / 64, 256, 0, stream>>>(ha, agg, res, W2h + (size_t)l * 64 * 128,
                                                   bconv + l * 64, lng, lnb, hb);
        f16* t = ha; ha = hb; hb = t;
    }
    k_out<<<N_NODES / 256, 256, 0, stream>>>(ha, Wout, bout, out);
}